// Round 4
// baseline (282.915 us; speedup 1.0000x reference)
//
#include <hip/hip_runtime.h>

// Fused grouped-QKV GEMM: out[t,kv,g,d] = sum_e in[t,e]*W[e,kv,g,d] + bias
// M=64, K=4096, N=6144. fp32 in/out.
//
// R11: single-kernel split-k with semaphore reduce. Evidence so far:
// R7(sync GLDS)=R8(pipelined GLDS)=R9(reg-staged)=163+-1us, and R10 proved
// the 2x 384MiB ws poison fills (~118us) are unconditional harness floor.
// The gemm is BW-bound (~127MB stream), so schedule changes are null; the
// remaining controllable costs are traffic + launches. This round:
//  - KSPLIT 16->8, NT 48->96 (64-wide tiles, 512k/block): same 768 blocks
//    (3/CU exact), partial tensor halves to 12.6MB each way.
//  - reduce fused into gemm: partials stored nontemporal, release fence
//    (__threadfence -> wbl2), per-column atomic counter; the 8th arriver
//    acquire-fences (inv) and reduces its 64-col slice + bias -> out.
//    No spinning: 7 blocks exit, the last one reduces -> schedule-safe.
//  - counters zeroed via 384B hipMemsetAsync (graph-capturable).
// K-loop body unchanged from R9 (verified): reg-staged W, depth-2 prefetch,
// XOR-swizzled LDS (2-way banks, free), cvt_pk A-pack.

#define N_COLS 6144
#define K_DIM  4096
#define Q_SZ   (64 * 4096)
#define K_OFF  Q_SZ
#define V_OFF  (Q_SZ + 64 * 1024)
#define NT     96          // n-tiles of 64
#define KSPLIT 8           // 512 k per block -> 768 blocks (3/CU, exact fill)
#define BK     32
#define TILES  16          // 512/32
#define PART_FLOATS (KSPLIT * NT * 4096)   // 3,145,728 fp32 = 12.6MB

typedef __bf16 bf16x8 __attribute__((ext_vector_type(8)));
typedef float  f32x4  __attribute__((ext_vector_type(4)));

__device__ __forceinline__ int out_index(int t, int n) {
    const int kv = n / 768;
    const int g  = (n >> 7) % 6;
    const int d  = n & 127;
    if (g < 4)  return t * 4096 + kv * 512 + g * 128 + d;   // q
    if (g == 4) return K_OFF + t * 1024 + kv * 128 + d;     // k
    return V_OFF + t * 1024 + kv * 128 + d;                 // v
}

__global__ __launch_bounds__(256, 3)
void qkv_gemm(const float* __restrict__ in, const float* __restrict__ w,
              const float* __restrict__ bias, float* __restrict__ out,
              float* __restrict__ part, unsigned* __restrict__ cnt) {
    __shared__ float Ws[2][BK * 64];   // 2 x 8KB fp32 W-tile, [k][n] k-major
    __shared__ int s_last;

    const int tid  = threadIdx.x;
    const int nt   = blockIdx.x % NT;    // adjacent blocks: adjacent n, same k
    const int kq   = blockIdx.x / NT;
    const int n0   = nt * 64;
    const int k0   = kq * (BK * TILES);  // kq*512
    const int wid  = tid >> 6;
    const int lane = tid & 63;
    const int l15  = lane & 15;
    const int kblk = lane >> 4;

    // W staging: thread owns 2 16B chunks, r=0..1: row k = r*16 + (tid>>4),
    // chunk col c = tid&15 (cols 4c..4c+3). LDS word [k*64 + (m ^
    // (((k>>3)&3)<<4))] holds W[k][m]; ds_write applies the XOR at chunk
    // granularity (c' = c ^ (((k>>3)&3)<<2)). Read side: col' = nb ^
    // (kblk<<4) -> kblk {0,2} banks 0-15, {1,3} banks 16-31: 2 lanes/bank
    // (free, m136).
    const int t4 = tid >> 4;
    const int c  = tid & 15;

    f32x4 acc[4];
    #pragma unroll
    for (int b = 0; b < 4; ++b) acc[b] = (f32x4){0.f, 0.f, 0.f, 0.f};

    f32x4 wreg[2][2];          // 2 sets x 2 chunks (depth-2 W prefetch)
    float4 alo[4], ahi[4];     // single A set (reloaded right after pack)

    const float* wbase = w + (size_t)k0 * N_COLS + n0 + c * 4;

    auto WLOAD = [&](int s, int set) {
        const float* p = wbase + (size_t)s * BK * N_COLS;
        #pragma unroll
        for (int r = 0; r < 2; ++r)
            wreg[set][r] = *(const f32x4*)(p + (size_t)(r * 16 + t4) * N_COLS);
    };
    auto DSWRITE = [&](int set, int buf) {
        #pragma unroll
        for (int r = 0; r < 2; ++r) {
            const int k  = r * 16 + t4;
            const int cc = c ^ (((k >> 3) & 3) << 2);
            *(f32x4*)&Ws[buf][k * 64 + 4 * cc] = wreg[set][r];
        }
    };
    auto ALOAD = [&](int s) {
        const int kc = k0 + s * BK;
        #pragma unroll
        for (int mi = 0; mi < 4; ++mi) {
            const float* ap = in + (size_t)(mi * 16 + l15) * K_DIM + kc + kblk * 8;
            alo[mi] = *(const float4*)ap;
            ahi[mi] = *(const float4*)(ap + 4);
        }
    };

    // STEP(s, p) with p == s&1 (compile-time at both call sites):
    // pack A(s) -> issue WLOAD(s+2)/ALOAD(s+1) -> MFMA from Ws[p] ->
    // commit tile s+1 (set p^1) into buf p^1 -> lgkmcnt(0) + barrier.
    auto STEP = [&](int s, int p) {
        bf16x8 av[4];
        #pragma unroll
        for (int mi = 0; mi < 4; ++mi) {
            av[mi][0] = (__bf16)alo[mi].x; av[mi][1] = (__bf16)alo[mi].y;
            av[mi][2] = (__bf16)alo[mi].z; av[mi][3] = (__bf16)alo[mi].w;
            av[mi][4] = (__bf16)ahi[mi].x; av[mi][5] = (__bf16)ahi[mi].y;
            av[mi][6] = (__bf16)ahi[mi].z; av[mi][7] = (__bf16)ahi[mi].w;
        }
        if (s + 2 < TILES) WLOAD(s + 2, p);     // in flight across barrier
        if (s + 1 < TILES) ALOAD(s + 1);

        const int nb   = wid * 16 + l15;        // wave wid owns one n-frag
        const int base = kblk * 8 * 64 + (nb ^ (kblk << 4));
        bf16x8 bv;
        #pragma unroll
        for (int j = 0; j < 8; ++j)
            bv[j] = (__bf16)Ws[p][base + j * 64];
        #pragma unroll
        for (int mi = 0; mi < 4; ++mi)
            acc[mi] = __builtin_amdgcn_mfma_f32_16x16x32_bf16(
                av[mi], bv, acc[mi], 0, 0, 0);

        if (s + 1 < TILES) {
            DSWRITE(p ^ 1, p ^ 1);              // waits only WLOAD(s+1)
            asm volatile("s_waitcnt lgkmcnt(0)" ::: "memory");
            __builtin_amdgcn_s_barrier();
        }
    };

    // prologue: tile0 -> buf0 (one exposed latency), tile1 loads in flight
    WLOAD(0, 0);
    ALOAD(0);
    WLOAD(1, 1);
    DSWRITE(0, 0);
    asm volatile("s_waitcnt lgkmcnt(0)" ::: "memory");
    __builtin_amdgcn_s_barrier();

    for (int ss = 0; ss < TILES; ss += 2) {
        STEP(ss, 0);
        STEP(ss + 1, 1);
    }

    // partials: C/D col = l15 (n), row = kblk*4 + r (token within m-frag).
    // layout part[kq][nt][t(64)][n(64)] -> column slice contiguous (16KB).
    float* pb = part + ((size_t)(kq * NT + nt)) * 4096 + wid * 16 + l15;
    #pragma unroll
    for (int mi = 0; mi < 4; ++mi) {
        #pragma unroll
        for (int r = 0; r < 4; ++r) {
            const int t = mi * 16 + kblk * 4 + r;
            __builtin_nontemporal_store(acc[mi][r], pb + t * 64);
        }
    }

    // split-k semaphore: release stores, count arrivers; 8th reduces.
    __threadfence();                       // release: partials -> coherence pt
    __syncthreads();                       // all waves' stores fenced
    if (tid == 0) {
        const unsigned prev = atomicAdd(&cnt[nt], 1u);   // device scope (m20)
        s_last = (prev == KSPLIT - 1);
    }
    __syncthreads();
    if (!s_last) return;
    __threadfence();                       // acquire: inv stale L1/L2 lines

    // reduce column nt: 64t x 64n = 4096 fp32; 256 thr x 4 f32x4, coalesced.
    f32x4 s4[4];
    #pragma unroll
    for (int h = 0; h < 4; ++h) {
        const int v = h * 256 + tid;
        s4[h] = *(const f32x4*)(bias + n0 + (v & 15) * 4);
    }
    #pragma unroll
    for (int kq2 = 0; kq2 < KSPLIT; ++kq2) {
        const float* pp = part + ((size_t)(kq2 * NT + nt)) * 4096;
        #pragma unroll
        for (int h = 0; h < 4; ++h)
            s4[h] += *(const f32x4*)(pp + (h * 256 + tid) * 4);
    }
    #pragma unroll
    for (int h = 0; h < 4; ++h) {
        const int v = h * 256 + tid;
        const int t = v >> 4;
        const int n = n0 + (v & 15) * 4;
        *(f32x4*)(out + out_index(t, n)) = s4[h];
    }
}

extern "C" void kernel_launch(void* const* d_in, const int* in_sizes, int n_in,
                              void* d_out, int out_size, void* d_ws, size_t ws_size,
                              hipStream_t stream) {
    const float* in   = (const float*)d_in[0];  // [64, 4096]
    const float* w    = (const float*)d_in[1];  // [4096, 8, 6, 128]
    const float* bias = (const float*)d_in[2];  // [8, 6, 128]
    float* out  = (float*)d_out;
    float* part = (float*)d_ws;                 // 12.6MB partials
    unsigned* cnt = (unsigned*)((char*)d_ws + (size_t)PART_FLOATS * 4);

    hipMemsetAsync(cnt, 0, NT * sizeof(unsigned), stream);  // capturable
    qkv_gemm<<<NT * KSPLIT, 256, 0, stream>>>(in, w, bias, out, part, cnt);
}

// Round 5
// 161.540 us; speedup vs baseline: 1.7514x; 1.7514x over previous
//
#include <hip/hip_runtime.h>

// Fused grouped-QKV GEMM: out[t,kv,g,d] = sum_e in[t,e]*W[e,kv,g,d] + bias
// M=64, K=4096, N=6144. fp32 in/out.
//
// R12: R9's verified 2-kernel reg-staged pipeline, re-tiled to cut partial
// traffic 4x. Evidence: R7=R8=R9=163+-1 (gemm schedule-invariant, BW-ish);
// R10 proved the 2x384MiB poison fills (~118us) are unconditional floor;
// R11 proved in-kernel cross-block coherence costs per-block L2
// writebacks/invalidates (gemm 175us, all pipes idle) -- never fence.
// This round: NT 48->192 (32-col tiles), KSPLIT 16->4 (K=1024/block),
// BK=64. Same 768 blocks (3/CU exact), same W stream (128KB/block, 128B
// row segments = full L2-line granularity), but partials 25.2 -> 6.3MB
// each way (-38MB HBM). NT%8==0 makes all 4 k-blocks of a column AND its
// reduce blocks share an XCD (bid%8=nt%8) -> partial L2 hits for free.
// K-loop structure unchanged from R9: reg-staged W, depth-2 prefetch,
// XOR-swizzled LDS (2-way banks, free), cvt_pk A-pack, plain stores.

#define N_COLS 6144
#define K_DIM  4096
#define Q_SZ   (64 * 4096)
#define K_OFF  Q_SZ
#define V_OFF  (Q_SZ + 64 * 1024)
#define OUT_ELEMS 393216   // 64*6144
#define NT     192         // n-tiles of 32
#define KSPLIT 4           // 1024 k per block -> 768 blocks (3/CU, exact)
#define BK     64
#define TILES  16          // 1024/64

typedef __bf16 bf16x8 __attribute__((ext_vector_type(8)));
typedef float  f32x4  __attribute__((ext_vector_type(4)));

__device__ __forceinline__ int out_index(int t, int n) {
    const int kv = n / 768;
    const int g  = (n >> 7) % 6;
    const int d  = n & 127;
    if (g < 4)  return t * 4096 + kv * 512 + g * 128 + d;   // q
    if (g == 4) return K_OFF + t * 1024 + kv * 128 + d;     // k
    return V_OFF + t * 1024 + kv * 128 + d;                 // v
}

__global__ __launch_bounds__(256, 3)
void qkv_gemm(const float* __restrict__ in, const float* __restrict__ w,
              float* __restrict__ part) {
    __shared__ float Ws[2][BK * 32];   // 2 x 8KB fp32 W-tile, [k][n] k-major

    const int tid  = threadIdx.x;
    const int nt   = blockIdx.x % NT;    // bid%8 = nt%8 (192%8==0): k-split
    const int kq   = blockIdx.x / NT;    // blocks of a column share an XCD
    const int n0   = nt * 32;
    const int k0   = kq * (BK * TILES);  // kq*1024
    const int wid  = tid >> 6;
    const int lane = tid & 63;
    const int l15  = lane & 15;
    const int kblk = lane >> 4;

    // W staging: thread owns 2 16B chunks, r=0..1: row k = r*32 + (tid>>3),
    // chunk c = tid&7 (cols 4c..4c+3 of 32). Swizzle: LDS word
    // [k*32 + (m ^ (((k>>3)&1)<<4))] holds W[k][m]; ds_write applies it at
    // chunk granularity (c' = c ^ (((k>>3)&1)<<2)). Read side: frag rows
    // kblk*8..+7 (and +32) all have (row>>3)&1 == kblk&1, so col' =
    // nb ^ ((kblk&1)<<4): kblk {0,2} banks c, {1,3} banks c^16 ->
    // 2 lanes/bank (free, m136).
    const int t3 = tid >> 3;   // 0..31
    const int c  = tid & 7;

    f32x4 acc[2];
    acc[0] = (f32x4){0.f, 0.f, 0.f, 0.f};
    acc[1] = (f32x4){0.f, 0.f, 0.f, 0.f};

    f32x4 wreg[2][2];          // 2 sets x 2 chunks (depth-2 W prefetch)
    float4 a[4];               // A rows for this wave's m-frag, one k-step

    const float* wbase = w + (size_t)k0 * N_COLS + n0 + c * 4;
    const float* abase = in + (size_t)(wid * 16 + l15) * K_DIM + k0 + kblk * 8;

    auto WLOAD = [&](int s, int set) {
        const float* p = wbase + (size_t)s * BK * N_COLS;
        #pragma unroll
        for (int r = 0; r < 2; ++r)
            wreg[set][r] = *(const f32x4*)(p + (size_t)(r * 32 + t3) * N_COLS);
    };
    auto DSWRITE = [&](int set, int buf) {
        #pragma unroll
        for (int r = 0; r < 2; ++r) {
            const int k  = r * 32 + t3;
            const int cc = c ^ (((k >> 3) & 1) << 2);
            *(f32x4*)&Ws[buf][k * 32 + 4 * cc] = wreg[set][r];
        }
    };
    auto ALOAD = [&](int s) {
        const float* ap = abase + (size_t)s * BK;
        a[0] = *(const float4*)ap;            // half0: k  0..7  (kblk slice)
        a[1] = *(const float4*)(ap + 4);
        a[2] = *(const float4*)(ap + 32);     // half1: k 32..39 (kblk slice)
        a[3] = *(const float4*)(ap + 36);
    };

    // prologue: tile0 -> buf0 (one exposed latency), tile1 loads in flight
    WLOAD(0, 0);
    ALOAD(0);
    WLOAD(1, 1);
    DSWRITE(0, 0);             // auto vmcnt wait: only wreg[0]'s loads
    asm volatile("s_waitcnt lgkmcnt(0)" ::: "memory");
    __builtin_amdgcn_s_barrier();

    #pragma unroll
    for (int s = 0; s < TILES; ++s) {
        // 1. pack A(s): two k-halves; (__bf16) cast = HW RNE cvt_pk
        bf16x8 av[2];
        #pragma unroll
        for (int h = 0; h < 2; ++h) {
            av[h][0] = (__bf16)a[2*h].x;   av[h][1] = (__bf16)a[2*h].y;
            av[h][2] = (__bf16)a[2*h].z;   av[h][3] = (__bf16)a[2*h].w;
            av[h][4] = (__bf16)a[2*h+1].x; av[h][5] = (__bf16)a[2*h+1].y;
            av[h][6] = (__bf16)a[2*h+1].z; av[h][7] = (__bf16)a[2*h+1].w;
        }

        // 2. prefetch issues (stay in flight across the barrier below)
        if (s + 2 < TILES) WLOAD(s + 2, s & 1);
        if (s + 1 < TILES) ALOAD(s + 1);

        // 3. B-frags from Ws[s&1] + MFMA; every wave uses both n-frags
        #pragma unroll
        for (int h = 0; h < 2; ++h) {
            #pragma unroll
            for (int nfi = 0; nfi < 2; ++nfi) {
                const int nb   = nfi * 16 + l15;
                const int base = (h * 32 + kblk * 8) * 32 + (nb ^ ((kblk & 1) << 4));
                bf16x8 bv;
                #pragma unroll
                for (int j = 0; j < 8; ++j)
                    bv[j] = (__bf16)Ws[s & 1][base + j * 32];
                acc[nfi] = __builtin_amdgcn_mfma_f32_16x16x32_bf16(
                    av[h], bv, acc[nfi], 0, 0, 0);
            }
        }

        // 4/5. commit tile s+1 into the other buffer; one barrier per tile
        if (s + 1 < TILES) {
            DSWRITE((s + 1) & 1, (s + 1) & 1);  // waits only WLOAD(s+1)
            asm volatile("s_waitcnt lgkmcnt(0)" ::: "memory");
            __builtin_amdgcn_s_barrier();
        }
    }

    // partials: C/D col = l15 (n), row = kblk*4 + r; wave wid owns rows
    // wid*16..wid*16+15. Plain stores (keep L2-resident for the reducer).
    float* pb = part + (size_t)kq * OUT_ELEMS;
    #pragma unroll
    for (int nfi = 0; nfi < 2; ++nfi) {
        const int n = n0 + nfi * 16 + l15;
        #pragma unroll
        for (int r = 0; r < 4; ++r) {
            const int t = wid * 16 + kblk * 4 + r;
            pb[(size_t)t * N_COLS + n] = acc[nfi][r];
        }
    }
}

// sum KSPLIT partials + bias, scatter to q|k|v. Grid 384: nt = bid%192 so
// bid%8 = nt%8 -> same XCD as the gemm blocks that wrote column nt (L2 hits
// on surviving partial lines). Each block: half h = bid/192 of column nt.
__global__ __launch_bounds__(256)
void qkv_reduce(const float* __restrict__ part, const float* __restrict__ bias,
                float* __restrict__ out) {
    const int nt = blockIdx.x % NT;
    const int h  = blockIdx.x / NT;
    const int t  = h * 32 + (threadIdx.x >> 3);
    const int n  = nt * 32 + (threadIdx.x & 7) * 4;
    const size_t i = (size_t)t * N_COLS + n;
    f32x4 s = *(const f32x4*)(bias + n);
    #pragma unroll
    for (int kq = 0; kq < KSPLIT; ++kq)
        s += *(const f32x4*)(part + (size_t)kq * OUT_ELEMS + i);
    *(f32x4*)(out + out_index(t, n)) = s;   // 4-chunk never crosses d-block
}

extern "C" void kernel_launch(void* const* d_in, const int* in_sizes, int n_in,
                              void* d_out, int out_size, void* d_ws, size_t ws_size,
                              hipStream_t stream) {
    const float* in   = (const float*)d_in[0];  // [64, 4096]
    const float* w    = (const float*)d_in[1];  // [4096, 8, 6, 128]
    const float* bias = (const float*)d_in[2];  // [8, 6, 128]
    float* out  = (float*)d_out;
    float* part = (float*)d_ws;                 // 4 * 1.57MB = 6.3MB fp32

    qkv_gemm<<<NT * KSPLIT, 256, 0, stream>>>(in, w, part);
    qkv_reduce<<<NT * 2, 256, 0, stream>>>(part, bias, out);
}